// Round 14
// baseline (558.847 us; speedup 1.0000x reference)
//
#include <hip/hip_runtime.h>
#include <math.h>

#define PIXN 4096

typedef _Float16 f16;
typedef short s16x8 __attribute__((ext_vector_type(8)));
typedef unsigned short u16x4 __attribute__((ext_vector_type(4)));
typedef float f32x4 __attribute__((ext_vector_type(4)));

__device__ __forceinline__ f16 f2h(float f) { return (f16)f; }
__device__ __forceinline__ float h2f(f16 h) { return (float)h; }

// bf16 round-to-nearest-even via bit trick; residual f - bf2f(f2bf(f)) is exact in fp32.
__device__ __forceinline__ unsigned short f2bf(float f) {
  unsigned u = __float_as_uint(f);
  u += 0x7fffu + ((u >> 16) & 1u);
  return (unsigned short)(u >> 16);
}
__device__ __forceinline__ float bf2f(unsigned short h) {
  return __uint_as_float(((unsigned)h) << 16);
}

enum { ACT_NONE = 0, ACT_LRELU = 1, ACT_SIG144 = 2 };
enum { IN_FLAT = 1, IN_UVPAIR = 2, IN_QKV = 3, IN_BF = 4, IN_MERGE = 5 };
enum { OUT_FLAT = 0, OUT_NCHWRES = 1, OUT_BF = 2 };

// ---------------- weight prep ----------------
// MFMA weight prep: layout [tap][kc][kch][co][8e], hi plane then lo plane (each `total` elems).
__device__ __forceinline__ void wprep_mfma(const float* __restrict__ w, unsigned short* __restrict__ dst,
                                           int srcCIN, int cinOff, int COUTv, int COUTP,
                                           int total, int idx) {
  if (idx >= total) return;
  int e = idx & 7;
  int t = idx >> 3;
  int co = t % COUTP; t /= COUTP;
  int kch = t & 3; t >>= 2;
  int kc = t % 3;
  int tap = t / 3;
  int ci = kc * 32 + kch * 8 + e;
  float v = 0.f;
  if (co < COUTv) v = w[((long)co * srcCIN + cinOff + ci) * 9 + tap];
  unsigned short h = f2bf(v);
  dst[idx] = h;
  dst[total + idx] = f2bf(v - bf2f(h));
}

__global__ __launch_bounds__(256) void prep_all(
    const float* __restrict__ cf_w, const float* __restrict__ oc1_w,
    const float* __restrict__ oc2_w, const float* __restrict__ om_w,
    const float* __restrict__ cl_w,
    const float* __restrict__ wq, const float* __restrict__ wk, const float* __restrict__ wv,
    const float* __restrict__ bq, const float* __restrict__ bk, const float* __restrict__ bv,
    const float* __restrict__ cf_b,
    unsigned short* __restrict__ WBQ, float* __restrict__ BQ,
    unsigned short* __restrict__ WB1, unsigned short* __restrict__ WB2,
    unsigned short* __restrict__ WB3, unsigned short* __restrict__ WB4) {
  int idx = blockIdx.x * 256 + threadIdx.x;
  switch (blockIdx.y) {
    case 0: {  // composite qkv conv: W'[co,ci,tap] = sum_e wsel[co,e] * cf_w[e,ci,tap]
      if (idx < 288) {
        int m = idx / 96, ep = idx % 96;
        const float* wm = (m == 0) ? wq : (m == 1) ? wk : wv;
        const float* bm = (m == 0) ? bq : (m == 1) ? bk : bv;
        float s = bm[ep];
        for (int c = 0; c < 96; ++c) s = fmaf(wm[ep * 96 + c], cf_b[c], s);
        BQ[idx] = s;
      }
      if (idx < 165888) {
        int e = idx & 7;
        int t = idx >> 3;
        int co = t % 288; t /= 288;
        int kch = t & 3; t >>= 2;
        int kc = t & 1, tap = t >> 1;     // [tap][kc(2)][kch]
        int ci = kc * 32 + kch * 8 + e;
        int m = co / 96, ep = co % 96;
        const float* wm = (m == 0) ? wq : (m == 1) ? wk : wv;
        float s = 0.f;
        for (int c = 0; c < 96; ++c)
          s = fmaf(wm[ep * 96 + c], cf_w[((long)c * 64 + ci) * 9 + tap], s);
        unsigned short h = f2bf(s);
        WBQ[idx] = h;
        WBQ[165888 + idx] = f2bf(s - bf2f(h));
      }
      break;
    }
    case 1: wprep_mfma(oc1_w, WB1, 192, 0, 96, 96, 82944, idx); break;
    case 2: wprep_mfma(oc1_w, WB1 + 2 * 82944, 192, 96, 96, 96, 82944, idx); break;
    case 3: wprep_mfma(oc2_w, WB2, 96, 0, 96, 96, 82944, idx); break;
    case 4: wprep_mfma(om_w, WB3, 96, 0, 216, 256, 221184, idx); break;
    default: wprep_mfma(cl_w, WB4, 96, 0, 64, 64, 55296, idx); break;
  }
}

// ---------------- fea NCHW fp32 -> interleaved bf16 [img][px][kc(2)][hi32|lo32] ----------------
__global__ __launch_bounds__(256) void nchw2bf(const float* __restrict__ fea,
                                               unsigned short* __restrict__ bf) {
  const int y = blockIdx.x;
  const int img = blockIdx.y;
  const int t = threadIdx.x;
  const int x = t & 63, cg = t >> 6;
  __shared__ unsigned short sh[64][68], sl[64][68];
  const float* base = fea + ((long)img * 64) * PIXN + y * 64;
#pragma unroll
  for (int k = 0; k < 16; ++k) {
    int ci = cg * 16 + k;
    float v = base[(long)ci * PIXN + x];
    unsigned short h = f2bf(v);
    sh[x][ci] = h;
    sl[x][ci] = f2bf(v - bf2f(h));
  }
  __syncthreads();
  const long ob = (long)img * PIXN + y * 64;
  for (int i = t; i < 2048; i += 256) {
    int plane = i >> 10;
    int r = i & 1023;
    int px = r >> 4, q4 = r & 15;   // q4: ci 4-group 0..15
    u16x4 v4 = *reinterpret_cast<const u16x4*>(plane ? &sl[px][q4 * 4] : &sh[px][q4 * 4]);
    // record layout: [kc][hi 32ci | lo 32ci]
    long dst = (ob + px) * 128 + (q4 >> 3) * 64 + plane * 32 + (q4 & 7) * 4;
    *reinterpret_cast<u16x4*>(bf + dst) = v4;
  }
}

// ---------------- bf16x3-split MFMA 3x3 conv, B direct-from-L2 ----------------
// Block: 512 thr = 8 waves as (WM=8/WN) m-waves x WN n-waves; tile = 128 px x COG.
// A in LDS per-kc (34 KB).  B fragments lane-addressable in [tap][kc][kch][co][8].
// PF=0: full-step prefetch (pb bank -> cb rotate).  PF=1: circular per-nt refill
// (cluster nt consumes pb[nt] then reloads next step's nt; cover = NTW-1 clusters).
// WN=1 + PF=1 (om): 8 m-waves share identical B addresses (L1 broadcast) and
// A-LDS traffic is 1x (vs WN x redundancy).
// IN_BF: interleaved records [px][kc][hi32|lo32] -> dense 128B fetch, copy-only staging.
// IN_MERGE: per-pixel softmax (s_sm LDS, computed ONCE) + f16 vre blend in staging.
// OUT_BF: epilogue writes the interleaved record layout (value-identical).
template <int CIN, int COUT, int COUTW, int NCOG, int IMODE, int ACT, int OMODE, int WN, int PF>
__global__ __launch_bounds__(512, 4) void conv3x3r(
    const float* __restrict__ in, const float* __restrict__ in2,
    const float* __restrict__ bias_in,
    const unsigned short* __restrict__ WB,
    const float* __restrict__ bias,
    float* __restrict__ out,
    const float* __restrict__ resid) {
  constexpr int KC = CIN / 32;             // 2 or 3
  constexpr int WM = 8 / WN;
  constexpr int MT = WN;                   // m-tiles per wave (M=128 total)
  constexpr int COG = COUTW / NCOG;
  constexpr int NTW = COG / (WN * 16);     // n-tiles per wave
  constexpr int AST = 4 * 66 * 8 + 8;      // padded ci8 stride (elems)
  constexpr int APL = 4 * AST;             // per-plane A elems (one kc = 4 ci8)
  constexpr int BSTEP = COUTW * 32;        // per-plane B elems per K-step
  constexpr int TOTB = 9 * KC * BSTEP;     // per-plane B elems total

  __shared__ __align__(16) unsigned short Abuf[2 * APL];
  __shared__ float s_sm[(IMODE == IN_MERGE) ? 528 : 4];  // per-pixel s0/s1

  const int tid = threadIdx.x;
  const int lane = tid & 63;
  const int wid = tid >> 6;
  const int wm = wid % WM;
  const int wn = wid / WM;
  const int iz = blockIdx.y;
  const int y0 = blockIdx.x * 2;
  const int zoff = (NCOG > 1) ? blockIdx.z * COG : 0;

  const float* baseA = nullptr;
  const float* baseB2 = nullptr;
  const unsigned short* hpl = nullptr;
  const unsigned short* wbe = WB;
  int LDV = CIN;
  if constexpr (IMODE == IN_UVPAIR) {
    int pair = iz >> 2, b = iz & 3;
    int jj = pair >> 1, rr2 = pair & 1;
    int ii = (rr2 == 0) ? (jj == 0 ? 1 : 0) : (jj == 2 ? 1 : 2);
    baseA = in + (long)(b * 3 + jj) * (PIXN * 96);
    baseB2 = in2 + (long)(b * 3 + ii) * (PIXN * 96);
    LDV = 96;
  } else if constexpr (IMODE == IN_QKV) {
    int sel = iz / 12, img = iz % 12;
    baseA = in + (long)img * (PIXN * 288) + sel * 96;
    wbe = WB + (long)sel * (2 * TOTB);
    LDV = 288;
  } else if constexpr (IMODE == IN_BF) {
    hpl = reinterpret_cast<const unsigned short*>(in) + (long)iz * ((long)PIXN * CIN * 2);
  } else if constexpr (IMODE == IN_MERGE) {
    // in = vre (f16), in2 = w_buf; iz = img (b*3+jj)
  } else {
    baseA = in + (long)iz * ((long)PIXN * CIN);
    LDV = CIN;
  }

  // ---- stage A for one kc group (32 ci) ----
  auto stageA = [&](int kc) {
    if constexpr (IMODE == IN_BF) {
      for (int i = tid; i < 4 * 66 * 4; i += 512) {
        int ci8 = i & 3;
        int t = i >> 2;
        int xp = t % 66, rr = t / 66;
        int y = y0 + rr - 1, x = xp - 1;
        s16x8 hv = {0, 0, 0, 0, 0, 0, 0, 0};
        s16x8 lv = {0, 0, 0, 0, 0, 0, 0, 0};
        if ((unsigned)y < 64u && (unsigned)x < 64u) {
          // interleaved record: px*(CIN*2) + kc*64 + [hi: ci8*8 | lo: +32]
          long off = (long)(y * 64 + x) * (CIN * 2) + kc * 64 + ci8 * 8;
          hv = *reinterpret_cast<const s16x8*>(hpl + off);
          lv = *reinterpret_cast<const s16x8*>(hpl + off + 32);
        }
        int base = ci8 * AST + (rr * 66 + xp) * 8;
        *reinterpret_cast<s16x8*>(&Abuf[base]) = hv;
        *reinterpret_cast<s16x8*>(&Abuf[APL + base]) = lv;
      }
    } else if constexpr (IMODE == IN_MERGE) {
      const f16* vrep = reinterpret_cast<const f16*>(in);
      const int bb = iz / 3, jjm = iz % 3;
      const int pr0 = jjm * 2;
      for (int i = tid; i < 4 * 66 * 8; i += 512) {
        int ci4 = i & 7;
        int t = i >> 3;
        int xp = t % 66, rr = t / 66;
        int y = y0 + rr - 1, x = xp - 1;
        float4 v = make_float4(0.f, 0.f, 0.f, 0.f);
        if ((unsigned)y < 64u && (unsigned)x < 64u) {
          long bpi = (long)bb * PIXN + y * 64 + x;
          float s0 = s_sm[t * 2], s1 = s_sm[t * 2 + 1];
          const f16* pa = vrep + ((long)pr0 * 16384 + bpi) * 96 + kc * 32 + ci4 * 4;
          const f16* pb = vrep + ((long)(pr0 + 1) * 16384 + bpi) * 96 + kc * 32 + ci4 * 4;
          v.x = s0 * h2f(pa[0]) + s1 * h2f(pb[0]);
          v.y = s0 * h2f(pa[1]) + s1 * h2f(pb[1]);
          v.z = s0 * h2f(pa[2]) + s1 * h2f(pb[2]);
          v.w = s0 * h2f(pa[3]) + s1 * h2f(pb[3]);
        }
        unsigned short h0 = f2bf(v.x), h1 = f2bf(v.y), h2 = f2bf(v.z), h3 = f2bf(v.w);
        u16x4 hv = {h0, h1, h2, h3};
        u16x4 lv = {f2bf(v.x - bf2f(h0)), f2bf(v.y - bf2f(h1)),
                    f2bf(v.z - bf2f(h2)), f2bf(v.w - bf2f(h3))};
        int base = (ci4 >> 1) * AST + (rr * 66 + xp) * 8 + (ci4 & 1) * 4;
        *reinterpret_cast<u16x4*>(&Abuf[base]) = hv;
        *reinterpret_cast<u16x4*>(&Abuf[APL + base]) = lv;
      }
    } else {
      for (int i = tid; i < 4 * 66 * 8; i += 512) {
        int ci4 = i & 7;
        int t = i >> 3;
        int xp = t % 66, rr = t / 66;
        int y = y0 + rr - 1, x = xp - 1;
        float4 v = make_float4(0.f, 0.f, 0.f, 0.f);
        if ((unsigned)y < 64u && (unsigned)x < 64u) {
          long off = (long)(y * 64 + x) * LDV + kc * 32 + ci4 * 4;
          if constexpr (IMODE == IN_UVPAIR) {
            float4 u = *reinterpret_cast<const float4*>(baseA + off);
            float4 w2 = *reinterpret_cast<const float4*>(baseB2 + off);
            float4 bi = *reinterpret_cast<const float4*>(bias_in + kc * 32 + ci4 * 4);
            v.x = u.x + w2.x + bi.x; v.x = v.x >= 0.f ? v.x : 0.1f * v.x;
            v.y = u.y + w2.y + bi.y; v.y = v.y >= 0.f ? v.y : 0.1f * v.y;
            v.z = u.z + w2.z + bi.z; v.z = v.z >= 0.f ? v.z : 0.1f * v.z;
            v.w = u.w + w2.w + bi.w; v.w = v.w >= 0.f ? v.w : 0.1f * v.w;
          } else {
            v = *reinterpret_cast<const float4*>(baseA + off);
          }
        }
        unsigned short h0 = f2bf(v.x), h1 = f2bf(v.y), h2 = f2bf(v.z), h3 = f2bf(v.w);
        u16x4 hv = {h0, h1, h2, h3};
        u16x4 lv = {f2bf(v.x - bf2f(h0)), f2bf(v.y - bf2f(h1)),
                    f2bf(v.z - bf2f(h2)), f2bf(v.w - bf2f(h3))};
        int base = (ci4 >> 1) * AST + (rr * 66 + xp) * 8 + (ci4 & 1) * 4;
        *reinterpret_cast<u16x4*>(&Abuf[base]) = hv;
        *reinterpret_cast<u16x4*>(&Abuf[APL + base]) = lv;
      }
    }
  };

  // ---- init acc ----
  f32x4 acc[MT][NTW];
#pragma unroll
  for (int nt = 0; nt < NTW; ++nt) {
    int co = zoff + (wn * NTW + nt) * 16 + (lane & 15);
    float b0 = 0.f;
    if (bias != nullptr && co < COUT) b0 = bias[co];
#pragma unroll
    for (int mt = 0; mt < MT; ++mt) {
      acc[mt][nt][0] = b0; acc[mt][nt][1] = b0;
      acc[mt][nt][2] = b0; acc[mt][nt][3] = b0;
    }
  }

  // ---- IN_MERGE: per-pixel softmax computed ONCE into LDS ----
  if constexpr (IMODE == IN_MERGE) {
    const float* wbp = in2;
    const int bb = iz / 3, jjm = iz % 3;
    const int pr0 = jjm * 2;
    for (int t = tid; t < 264; t += 512) {
      int rr = t / 66, xp = t - rr * 66;
      int y = y0 + rr - 1, x = xp - 1;
      float s0 = 0.f, s1 = 0.f;
      if ((unsigned)y < 64u && (unsigned)x < 64u) {
        long bpi = (long)bb * PIXN + y * 64 + x;
        float w0 = wbp[(long)pr0 * 16384 + bpi];
        float w1 = wbp[(long)(pr0 + 1) * 16384 + bpi];
        float mx = fmaxf(w0, w1);
        float e0 = expf(w0 - mx), e1 = expf(w1 - mx);
        float inv = 1.f / (e0 + e1);
        s0 = e0 * inv; s1 = e1 * inv;
      }
      s_sm[t * 2] = s0; s_sm[t * 2 + 1] = s1;
    }
    __syncthreads();
  }

  stageA(0);
  __syncthreads();

  // per-lane B fragment offset within a step (elems)
  const int blo = ((lane >> 4) * COUTW + zoff + (wn * NTW) * 16 + (lane & 15)) * 8;

  s16x8 cbh[(PF == 0) ? NTW : 1], cbl[(PF == 0) ? NTW : 1];
  s16x8 pbh[NTW], pbl[NTW];
#pragma unroll
  for (int nt = 0; nt < NTW; ++nt) {
    const unsigned short* p = wbe + (long)nt * 128 + blo;
    pbh[nt] = *reinterpret_cast<const s16x8*>(p);
    pbl[nt] = *reinterpret_cast<const s16x8*>(p + TOTB);
  }

  long bo = 0;
#pragma unroll 1
  for (int kc = 0; kc < KC; ++kc) {
#pragma unroll 1
    for (int tap = 0; tap < 9; ++tap) {
      const int dy = tap / 3, dx = tap % 3;
      const bool last = (kc == KC - 1) && (tap == 8);
      const long bo_next = (tap < 8) ? bo + (long)KC * BSTEP : (long)(kc + 1) * BSTEP;

      if constexpr (PF == 0) {
        // rotate prefetched bank into current (v_mov, overlaps MFMA pipe)
#pragma unroll
        for (int nt = 0; nt < NTW; ++nt) { cbh[nt] = pbh[nt]; cbl[nt] = pbl[nt]; }
        // issue ENTIRE next-step B loads now -> full-cluster latency window
        if (!last) {
#pragma unroll
          for (int nt = 0; nt < NTW; ++nt) {
            const unsigned short* np = wbe + bo_next + (long)nt * 128 + blo;
            pbh[nt] = *reinterpret_cast<const s16x8*>(np);
            pbl[nt] = *reinterpret_cast<const s16x8*>(np + TOTB);
          }
        }
      }

      // A fragments for this tap
      s16x8 ah[MT], al[MT];
      {
        int ci8 = lane >> 4;
        int m = lane & 15;
#pragma unroll
        for (int mt = 0; mt < MT; ++mt) {
          int px = (wm * MT + mt) * 16 + m;
          int r = px >> 6, x = px & 63;
          int aoff = ci8 * AST + ((r + dy) * 66 + (x + dx)) * 8;
          ah[mt] = *reinterpret_cast<const s16x8*>(&Abuf[aoff]);
          al[mt] = *reinterpret_cast<const s16x8*>(&Abuf[APL + aoff]);
        }
      }

#pragma unroll
      for (int nt = 0; nt < NTW; ++nt) {
        const s16x8 bh = (PF == 0) ? cbh[nt] : pbh[nt];
        const s16x8 bl = (PF == 0) ? cbl[nt] : pbl[nt];
#pragma unroll
        for (int mt = 0; mt < MT; ++mt) {
          acc[mt][nt] = __builtin_amdgcn_mfma_f32_16x16x32_bf16(ah[mt], bh, acc[mt][nt], 0, 0, 0);
          acc[mt][nt] = __builtin_amdgcn_mfma_f32_16x16x32_bf16(al[mt], bh, acc[mt][nt], 0, 0, 0);
          acc[mt][nt] = __builtin_amdgcn_mfma_f32_16x16x32_bf16(ah[mt], bl, acc[mt][nt], 0, 0, 0);
        }
        if constexpr (PF == 1) {
          // circular refill: cover = remaining NTW-1 clusters + next A-phase
          if (!last) {
            const unsigned short* np = wbe + bo_next + (long)nt * 128 + blo;
            pbh[nt] = *reinterpret_cast<const s16x8*>(np);
            pbl[nt] = *reinterpret_cast<const s16x8*>(np + TOTB);
          }
        }
      }
      bo = bo_next;
    }
    if (kc + 1 < KC) {
      __syncthreads();
      stageA(kc + 1);
      __syncthreads();
    }
  }

  // ---- epilogue ----
#pragma unroll
  for (int mt = 0; mt < MT; ++mt) {
#pragma unroll
    for (int nt = 0; nt < NTW; ++nt) {
      int co = zoff + (wn * NTW + nt) * 16 + (lane & 15);
      if (COUTW > COUT && co >= COUT) continue;
#pragma unroll
      for (int r = 0; r < 4; ++r) {
        int px = (wm * MT + mt) * 16 + (lane >> 4) * 4 + r;
        float v = acc[mt][nt][r];
        if constexpr (ACT == ACT_LRELU) v = v >= 0.f ? v : 0.1f * v;
        if constexpr (ACT == ACT_SIG144) {
          if (co >= 144) v = 1.f / (1.f + expf(-v));
        }
        if constexpr (OMODE == OUT_FLAT) {
          const long obase = (long)iz * PIXN + blockIdx.x * 128;
          out[(obase + px) * COUT + co] = v;
        } else if constexpr (OMODE == OUT_BF) {
          unsigned short* outh = reinterpret_cast<unsigned short*>(out);
          long prow = (long)iz * PIXN + blockIdx.x * 128 + px;
          long rec = prow * (COUT * 2) + (co >> 5) * 64 + (co & 31);
          unsigned short h = f2bf(v);
          outh[rec] = h;
          outh[rec + 32] = f2bf(v - bf2f(h));
        } else {
          long oo = (long)iz * ((long)COUT * PIXN) + (long)co * PIXN + blockIdx.x * 128 + px;
          out[oo] = v + resid[oo];
        }
      }
    }
  }
}

// ---------------- attn v3: 2 px/wave, 3 ch/lane, LDS-precomputed bilinear setup ----------------
// blockIdx.x XCD-swizzled: each XCD gets a contiguous 256-block chunk (2048 px)
// -> kimg gather rows (~2.7 MB) fit the per-XCD 4 MB L2.
#define CWSLOT 580  // 72*8 + 4 pad
__global__ __launch_bounds__(256) void attn3_k(const float* __restrict__ qkv,
                                               const float* __restrict__ om,
                                               float* __restrict__ w_buf,
                                               f16* __restrict__ vre) {
  const int pair = blockIdx.y;
  const int jj = pair >> 1, rr = pair & 1;
  const int ii = (rr == 0) ? (jj == 0 ? 1 : 0) : (jj == 2 ? 1 : 2);
  const int wv = threadIdx.x >> 6;
  const int lane = threadIdx.x & 63;
  const int xs = (blockIdx.x & 7) * 256 + (blockIdx.x >> 3);  // bijective, 2048%8==0
  const int bp0 = xs * 8 + wv * 2;  // even; both px same b

  __shared__ float s_om[8 * 216];
  __shared__ float s_cw[8 * CWSLOT];

  {
    const float* omrow = om + ((long)pair * 16384 + bp0) * 216;
    float* dst = s_om + wv * 432;
    for (int i = lane; i < 432; i += 64) dst[i] = omrow[i];
  }
  __syncthreads();

  for (int t = lane; t < 144; t += 64) {
    int ph = t / 72, cmb = t - ph * 72;
    int g = cmb / 9, n = cmb - g * 9;
    int p = (bp0 + ph) & 4095;
    int y = p >> 6, x = p & 63;
    const float* so = s_om + (wv * 2 + ph) * 216;
    float oy = so[g * 9 + n], ox = so[72 + g * 9 + n], m = so[144 + g * 9 + n];
    float py = oy + (float)(y + n / 3 - 1);
    float px = ox + (float)(x + n % 3 - 1);
    float y0f = floorf(py), x0f = floorf(px);
    float wy = py - y0f, wx = px - x0f;
    float* dst = s_cw + (wv * 2 + ph) * CWSLOT + cmb * 8;
#pragma unroll
    for (int dy = 0; dy < 2; ++dy) {
#pragma unroll
      for (int dx = 0; dx < 2; ++dx) {
        float yc = y0f + dy, xc = x0f + dx;
        bool valid = (yc >= 0.f) & (yc < 64.f) & (xc >= 0.f) & (xc < 64.f);
        float w = (dy ? wy : 1.f - wy) * (dx ? wx : 1.f - wx) * m;
        w = valid ? w : 0.f;
        int yi = (int)fminf(fmaxf(yc, 0.f), 63.f);
        int xi = (int)fminf(fmaxf(xc, 0.f), 63.f);
        int idx = (yi * 64 + xi) * 288 + 96;  // K base; V adds +96
        dst[dy * 2 + dx] = w;
        dst[4 + dy * 2 + dx] = __int_as_float(idx);
      }
    }
  }
  __syncthreads();

  const int ph = lane >> 5;
  const int li = lane & 31;
  const int bp = bp0 + ph;
  const int b = bp >> 12;
  const int cb = li * 3;
  const int g = li >> 2;
  const float* kimg = qkv + (long)(b * 3 + ii) * (PIXN * 288);
  const float* qrow = qkv + ((long)(b * 3 + jj) * PIXN + (bp & 4095)) * 288 + cb;
  const float q0 = qrow[0], q1 = qrow[1], q2 = qrow[2];
  const float* cw = s_cw + (wv * 2 + ph) * CWSLOT + g * 9 * 8;

  float ka[9][3];
  float rel[9];
#pragma unroll
  for (int n = 0; n < 9; ++n) {
    float4 w4 = *reinterpret_cast<const float4*>(cw + n * 8);
    float4 i4 = *reinterpret_cast<const float4*>(cw + n * 8 + 4);
    int ia = __float_as_int(i4.x) + cb, ib = __float_as_int(i4.y) + cb;
    int ic = __float_as_int(i4.z) + cb, id = __float_as_int(i4.w) + cb;
#pragma unroll
    for (int j = 0; j < 3; ++j) {
      float a = w4.x * kimg[ia + j];
      a = fmaf(w4.y, kimg[ib + j], a);
      a = fmaf(w4.z, kimg[ic + j], a);
      a = fmaf(w4.w, kimg[id + j], a);
      ka[n][j] = a;
    }
    float part = q0 * ka[n][0];
    part = fmaf(q1, ka[n][1], part);
    part = fmaf(q2, ka[n][2], part);
#pragma unroll
    for (int off = 16; off > 0; off >>= 1) part += __shfl_xor(part, off, 64);
    rel[n] = part;
  }

  int i0 = 0; float v0 = rel[0];
  float ks0a = ka[0][0], ks0b = ka[0][1], ks0c = ka[0][2];
#pragma unroll
  for (int n = 1; n < 9; ++n) {
    bool t = rel[n] > v0;
    v0 = t ? rel[n] : v0; i0 = t ? n : i0;
    ks0a = t ? ka[n][0] : ks0a; ks0b = t ? ka[n][1] : ks0b; ks0c = t ? ka[n][2] : ks0c;
  }
  int i1 = 0; float v1 = -3.4e38f;
  float ks1a = 0.f, ks1b = 0.f, ks1c = 0.f;
#pragma unroll
  for (int n = 0; n < 9; ++n) {
    bool t = (n != i0) && rel[n] > v1;
    v1 = t ? rel[n] : v1; i1 = t ? n : i1;
    ks1a = t ? ka[n][0] : ks1a; ks1b = t ? ka[n][1] : ks1b; ks1c = t ? ka[n][2] : ks1c;
  }
  float e = expf(v1 - v0);
  float cw0 = 1.f / (1.f + e), cw1 = e * cw0;

  float wpart = q0 * (cw0 * ks0a + cw1 * ks1a);
  wpart = fmaf(q1, cw0 * ks0b + cw1 * ks1b, wpart);
  wpart = fmaf(q2, cw0 * ks0c + cw1 * ks1c, wpart);
#pragma unroll
  for (int off = 16; off > 0; off >>= 1) wpart += __shfl_xor(wpart, off, 64);
  if (li == 0) w_buf[(long)pair * 16384 + bp] = wpart;

  float4 wA = *reinterpret_cast<const float4*>(cw + i0 * 8);
  float4 iA = *reinterpret_cast<const float4*>(cw + i0 * 8 + 4);
  float4 wB = *reinterpret_cast<const float4*>(cw + i1 * 8);
  float4 iB = *reinterpret_cast<const float4*>(cw + i1 * 8 + 4);
  int a0 = __float_as_int(iA.x) + 96 + cb, a1 = __float_as_int(iA.y) + 96 + cb;
  int a2 = __float_as_int(iA.z) + 96 + cb, a3 = __float_as_int(iA.w) + 96 + cb;
  int b0 = __float_as_int(iB.x) + 96 + cb, b1 = __float_as_int(iB.y) + 96 + cb;
  int b2 = __float_as_int(iB.z) + 96 + cb, b3 = __float_as_int(iB.w) + 96 + cb;
  f16* vrow = vre + ((long)pair * 16384 + bp) * 96 + cb;
#pragma unroll
  for (int j = 0; j < 3; ++j) {
    float va = wA.x * kimg[a0 + j];
    va = fmaf(wA.y, kimg[a1 + j], va);
    va = fmaf(wA.z, kimg[a2 + j], va);
    va = fmaf(wA.w, kimg[a3 + j], va);
    float vb = wB.x * kimg[b0 + j];
    vb = fmaf(wB.y, kimg[b1 + j], vb);
    vb = fmaf(wB.z, kimg[b2 + j], vb);
    vb = fmaf(wB.w, kimg[b3 + j], vb);
    vrow[j] = f2h(cw0 * va + cw1 * vb);
  }
}

// ---------------- host ----------------
extern "C" void kernel_launch(void* const* d_in, const int* in_sizes, int n_in,
                              void* d_out, int out_size, void* d_ws, size_t ws_size,
                              hipStream_t stream) {
  const float* fea = (const float*)d_in[0];
  const float* cf_w = (const float*)d_in[1];
  const float* cf_b = (const float*)d_in[2];
  const float* wq = (const float*)d_in[3];
  const float* bq = (const float*)d_in[4];
  const float* wk = (const float*)d_in[5];
  const float* bk = (const float*)d_in[6];
  const float* wv = (const float*)d_in[7];
  const float* bv = (const float*)d_in[8];
  const float* oc1_w = (const float*)d_in[9];
  const float* oc1_b = (const float*)d_in[10];
  const float* oc2_w = (const float*)d_in[11];
  const float* oc2_b = (const float*)d_in[12];
  const float* om_w = (const float*)d_in[13];
  const float* om_b = (const float*)d_in[14];
  const float* cl_w = (const float*)d_in[15];
  const float* cl_b = (const float*)d_in[16];

  char* base = (char*)d_ws;
  size_t o = 0;
  auto carve = [&](size_t bytes) { char* p = base + o; o += (bytes + 255) & ~255UL; return p; };

  unsigned short* WBQ = (unsigned short*)carve(2UL * 165888 * 2);  // composite qkv conv
  float* BQ = (float*)carve(288UL * 4);
  unsigned short* WB1 = (unsigned short*)carve(2UL * 2 * 82944 * 2);  // [sel][hi|lo]
  unsigned short* WB2 = (unsigned short*)carve(2UL * 82944 * 2);
  unsigned short* WB3 = (unsigned short*)carve(2UL * 221184 * 2);     // om, COUTP=256
  unsigned short* WB4 = (unsigned short*)carve(2UL * 55296 * 2);
  unsigned short* feaB = (unsigned short*)carve(12UL * PIXN * 128 * 2);  // interleaved bf16

  float* om_t = (float*)carve(21233664UL * 4);
  float* qkv_t = (float*)carve(14155776UL * 4);
  float* U_t = (float*)carve(4718592UL * 4);
  float* V_t = (float*)carve(4718592UL * 4);
  unsigned short* off2B = (unsigned short*)carve(24UL * PIXN * 192 * 2);  // interleaved bf16
  float* w_buf = (float*)carve(98304UL * 4);
  f16* vre_b = (f16*)V_t;

  // --- weight prep (6 jobs on grid.y; x covers max total 221184) ---
  prep_all<<<dim3(864, 6), 256, 0, stream>>>(cf_w, oc1_w, oc2_w, om_w, cl_w,
                                             wq, wk, wv, bq, bk, bv, cf_b,
                                             WBQ, BQ, WB1, WB2, WB3, WB4);

  // --- fea NCHW -> interleaved bf16 records ---
  nchw2bf<<<dim3(64, 12), 256, 0, stream>>>(fea, feaB);

  // --- fused emb+qkv conv (MFMA bf16x3, composite weights), co split in 3 ---
  conv3x3r<64, 288, 288, 3, IN_BF, ACT_NONE, OUT_FLAT, 2, 0><<<dim3(32, 12, 3), 512, 0, stream>>>(
      (const float*)feaB, nullptr, nullptr, WBQ, BQ, qkv_t, nullptr);

  // --- off1 split (MFMA bf16x3): U = convA(q_img), V = convB(k_img) ---
  conv3x3r<96, 96, 96, 1, IN_QKV, ACT_NONE, OUT_FLAT, 2, 0><<<dim3(32, 24, 1), 512, 0, stream>>>(
      qkv_t, nullptr, nullptr, WB1, nullptr, U_t, nullptr);

  // --- off2 (MFMA bf16x3) with fused off1 epilogue -> interleaved bf16 records ---
  conv3x3r<96, 96, 96, 1, IN_UVPAIR, ACT_LRELU, OUT_BF, 2, 0><<<dim3(32, 24, 1), 512, 0, stream>>>(
      U_t, V_t, oc1_b, WB2, oc2_b, (float*)off2B, nullptr);

  // --- om conv (MFMA bf16x3, WN=1: shared-B waves, 1x A-LDS; circular prefetch) + sigmoid ---
  conv3x3r<96, 216, 256, 2, IN_BF, ACT_SIG144, OUT_FLAT, 1, 1><<<dim3(32, 24, 2), 512, 0, stream>>>(
      (const float*)off2B, nullptr, nullptr, WB3, om_b, om_t, nullptr);

  // --- fused deformable attention (fp32; 2 px/wave, 3 ch/lane, LDS setup, XCD swizzle) ---
  attn3_k<<<dim3(2048, 6), 256, 0, stream>>>(qkv_t, om_t, w_buf, vre_b);

  // --- final conv (MFMA bf16x3) with FUSED merge staging (per-pixel softmax in LDS) ---
  conv3x3r<96, 64, 64, 1, IN_MERGE, ACT_NONE, OUT_NCHWRES, 2, 0><<<dim3(32, 12, 1), 512, 0, stream>>>(
      (const float*)vre_b, w_buf, nullptr, WB4, cl_b, (float*)d_out, fea);
}

// Round 15
// 489.529 us; speedup vs baseline: 1.1416x; 1.1416x over previous
//
#include <hip/hip_runtime.h>
#include <math.h>

#define PIXN 4096

typedef _Float16 f16;
typedef short s16x8 __attribute__((ext_vector_type(8)));
typedef unsigned short u16x4 __attribute__((ext_vector_type(4)));
typedef float f32x4 __attribute__((ext_vector_type(4)));

__device__ __forceinline__ f16 f2h(float f) { return (f16)f; }
__device__ __forceinline__ float h2f(f16 h) { return (float)h; }

// bf16 round-to-nearest-even via bit trick; residual f - bf2f(f2bf(f)) is exact in fp32.
__device__ __forceinline__ unsigned short f2bf(float f) {
  unsigned u = __float_as_uint(f);
  u += 0x7fffu + ((u >> 16) & 1u);
  return (unsigned short)(u >> 16);
}
__device__ __forceinline__ float bf2f(unsigned short h) {
  return __uint_as_float(((unsigned)h) << 16);
}

enum { ACT_NONE = 0, ACT_LRELU = 1, ACT_SIG144 = 2 };
enum { IN_FLAT = 1, IN_UVPAIR = 2, IN_QKV = 3, IN_BF = 4, IN_MERGE = 5 };
enum { OUT_FLAT = 0, OUT_NCHWRES = 1, OUT_BF = 2 };

// ---------------- weight prep + fea transpose (fused, 7 jobs) ----------------
// MFMA weight prep: layout [tap][kc][kch][co][8e], hi plane then lo plane (each `total` elems).
__device__ __forceinline__ void wprep_mfma(const float* __restrict__ w, unsigned short* __restrict__ dst,
                                           int srcCIN, int cinOff, int COUTv, int COUTP,
                                           int total, int idx) {
  if (idx >= total) return;
  int e = idx & 7;
  int t = idx >> 3;
  int co = t % COUTP; t /= COUTP;
  int kch = t & 3; t >>= 2;
  int kc = t % 3;
  int tap = t / 3;
  int ci = kc * 32 + kch * 8 + e;
  float v = 0.f;
  if (co < COUTv) v = w[((long)co * srcCIN + cinOff + ci) * 9 + tap];
  unsigned short h = f2bf(v);
  dst[idx] = h;
  dst[total + idx] = f2bf(v - bf2f(h));
}

__global__ __launch_bounds__(256) void prep_all(
    const float* __restrict__ cf_w, const float* __restrict__ oc1_w,
    const float* __restrict__ oc2_w, const float* __restrict__ om_w,
    const float* __restrict__ cl_w,
    const float* __restrict__ wq, const float* __restrict__ wk, const float* __restrict__ wv,
    const float* __restrict__ bq, const float* __restrict__ bk, const float* __restrict__ bv,
    const float* __restrict__ cf_b, const float* __restrict__ fea,
    unsigned short* __restrict__ WBQ, float* __restrict__ BQ,
    unsigned short* __restrict__ WB1, unsigned short* __restrict__ WB2,
    unsigned short* __restrict__ WB3, unsigned short* __restrict__ WB4,
    unsigned short* __restrict__ feaB) {
  __shared__ unsigned short sh[64][68], sl[64][68];
  int idx = blockIdx.x * 256 + threadIdx.x;
  switch (blockIdx.y) {
    case 0: {  // composite qkv conv: W'[co,ci,tap] = sum_e wsel[co,e] * cf_w[e,ci,tap]
      if (idx < 288) {
        int m = idx / 96, ep = idx % 96;
        const float* wm = (m == 0) ? wq : (m == 1) ? wk : wv;
        const float* bm = (m == 0) ? bq : (m == 1) ? bk : bv;
        float s = bm[ep];
        for (int c = 0; c < 96; ++c) s = fmaf(wm[ep * 96 + c], cf_b[c], s);
        BQ[idx] = s;
      }
      if (idx < 165888) {
        int e = idx & 7;
        int t = idx >> 3;
        int co = t % 288; t /= 288;
        int kch = t & 3; t >>= 2;
        int kc = t & 1, tap = t >> 1;     // [tap][kc(2)][kch]
        int ci = kc * 32 + kch * 8 + e;
        int m = co / 96, ep = co % 96;
        const float* wm = (m == 0) ? wq : (m == 1) ? wk : wv;
        float s = 0.f;
        for (int c = 0; c < 96; ++c)
          s = fmaf(wm[ep * 96 + c], cf_w[((long)c * 64 + ci) * 9 + tap], s);
        unsigned short h = f2bf(s);
        WBQ[idx] = h;
        WBQ[165888 + idx] = f2bf(s - bf2f(h));
      }
      break;
    }
    case 1: wprep_mfma(oc1_w, WB1, 192, 0, 96, 96, 82944, idx); break;
    case 2: wprep_mfma(oc1_w, WB1 + 2 * 82944, 192, 96, 96, 96, 82944, idx); break;
    case 3: wprep_mfma(oc2_w, WB2, 96, 0, 96, 96, 82944, idx); break;
    case 4: wprep_mfma(om_w, WB3, 96, 0, 216, 256, 221184, idx); break;
    case 5: wprep_mfma(cl_w, WB4, 96, 0, 64, 64, 55296, idx); break;
    default: {  // fea NCHW fp32 -> interleaved bf16 [img][px][kc(2)][hi32|lo32]
      if (blockIdx.x >= 768) return;
      const int y = blockIdx.x & 63;
      const int img = blockIdx.x >> 6;
      const int t = threadIdx.x;
      const int x = t & 63, cg = t >> 6;
      const float* base = fea + ((long)img * 64) * PIXN + y * 64;
#pragma unroll
      for (int k = 0; k < 16; ++k) {
        int ci = cg * 16 + k;
        float v = base[(long)ci * PIXN + x];
        unsigned short h = f2bf(v);
        sh[x][ci] = h;
        sl[x][ci] = f2bf(v - bf2f(h));
      }
      __syncthreads();
      const long ob = (long)img * PIXN + y * 64;
      for (int i = t; i < 2048; i += 256) {
        int plane = i >> 10;
        int r = i & 1023;
        int px = r >> 4, q4 = r & 15;   // q4: ci 4-group 0..15
        u16x4 v4 = *reinterpret_cast<const u16x4*>(plane ? &sl[px][q4 * 4] : &sh[px][q4 * 4]);
        long dst = (ob + px) * 128 + (q4 >> 3) * 64 + plane * 32 + (q4 & 7) * 4;
        *reinterpret_cast<u16x4*>(feaB + dst) = v4;
      }
      break;
    }
  }
}

// ---------------- bf16x3-split MFMA 3x3 conv, B direct-from-L2, full-step prefetch ----------------
// Block: 512 thr = 8 waves as (WM=8/WN) m-waves x WN n-waves; tile = 128 px x COG.
// A in LDS per-kc (34 KB).  B fragments lane-addressable in [tap][kc][kch][co][8]
// layout; entire NEXT K-step prefetched into a register bank (pb) while current
// (cb) feeds MFMAs -> L2 latency hidden by a full step's MFMA cluster.
// (PF=1 circular refill was tried r14: compiler demotes the NTW-deep bank -> 198us. Keep PF=0.)
// IN_BF: interleaved records [px][kc][hi32|lo32] -> dense 128B fetch, copy-only staging.
// IN_MERGE: per-pixel softmax (s_sm LDS, computed ONCE) + f16 vre blend in staging.
// OUT_BF: epilogue writes the interleaved record layout (value-identical).
template <int CIN, int COUT, int COUTW, int NCOG, int IMODE, int ACT, int OMODE, int WN>
__global__ __launch_bounds__(512, 4) void conv3x3r(
    const float* __restrict__ in, const float* __restrict__ in2,
    const float* __restrict__ bias_in,
    const unsigned short* __restrict__ WB,
    const float* __restrict__ bias,
    float* __restrict__ out,
    const float* __restrict__ resid) {
  constexpr int KC = CIN / 32;             // 2 or 3
  constexpr int WM = 8 / WN;
  constexpr int MT = WN;                   // m-tiles per wave (M=128 total)
  constexpr int COG = COUTW / NCOG;
  constexpr int NTW = COG / (WN * 16);     // n-tiles per wave
  constexpr int AST = 4 * 66 * 8 + 8;      // padded ci8 stride (elems)
  constexpr int APL = 4 * AST;             // per-plane A elems (one kc = 4 ci8)
  constexpr int BSTEP = COUTW * 32;        // per-plane B elems per K-step
  constexpr int TOTB = 9 * KC * BSTEP;     // per-plane B elems total

  __shared__ __align__(16) unsigned short Abuf[2 * APL];
  __shared__ float s_sm[(IMODE == IN_MERGE) ? 528 : 4];  // per-pixel s0/s1

  const int tid = threadIdx.x;
  const int lane = tid & 63;
  const int wid = tid >> 6;
  const int wm = wid % WM;
  const int wn = wid / WM;
  const int iz = blockIdx.y;
  const int y0 = blockIdx.x * 2;
  const int zoff = (NCOG > 1) ? blockIdx.z * COG : 0;

  const float* baseA = nullptr;
  const float* baseB2 = nullptr;
  const unsigned short* hpl = nullptr;
  const unsigned short* wbe = WB;
  int LDV = CIN;
  if constexpr (IMODE == IN_UVPAIR) {
    int pair = iz >> 2, b = iz & 3;
    int jj = pair >> 1, rr2 = pair & 1;
    int ii = (rr2 == 0) ? (jj == 0 ? 1 : 0) : (jj == 2 ? 1 : 2);
    baseA = in + (long)(b * 3 + jj) * (PIXN * 96);
    baseB2 = in2 + (long)(b * 3 + ii) * (PIXN * 96);
    LDV = 96;
  } else if constexpr (IMODE == IN_QKV) {
    int sel = iz / 12, img = iz % 12;
    baseA = in + (long)img * (PIXN * 288) + sel * 96;
    wbe = WB + (long)sel * (2 * TOTB);
    LDV = 288;
  } else if constexpr (IMODE == IN_BF) {
    hpl = reinterpret_cast<const unsigned short*>(in) + (long)iz * ((long)PIXN * CIN * 2);
  } else if constexpr (IMODE == IN_MERGE) {
    // in = vre (f16), in2 = w_buf; iz = img (b*3+jj)
  } else {
    baseA = in + (long)iz * ((long)PIXN * CIN);
    LDV = CIN;
  }

  // ---- stage A for one kc group (32 ci) ----
  auto stageA = [&](int kc) {
    if constexpr (IMODE == IN_BF) {
      for (int i = tid; i < 4 * 66 * 4; i += 512) {
        int ci8 = i & 3;
        int t = i >> 2;
        int xp = t % 66, rr = t / 66;
        int y = y0 + rr - 1, x = xp - 1;
        s16x8 hv = {0, 0, 0, 0, 0, 0, 0, 0};
        s16x8 lv = {0, 0, 0, 0, 0, 0, 0, 0};
        if ((unsigned)y < 64u && (unsigned)x < 64u) {
          // interleaved record: px*(CIN*2) + kc*64 + [hi: ci8*8 | lo: +32]
          long off = (long)(y * 64 + x) * (CIN * 2) + kc * 64 + ci8 * 8;
          hv = *reinterpret_cast<const s16x8*>(hpl + off);
          lv = *reinterpret_cast<const s16x8*>(hpl + off + 32);
        }
        int base = ci8 * AST + (rr * 66 + xp) * 8;
        *reinterpret_cast<s16x8*>(&Abuf[base]) = hv;
        *reinterpret_cast<s16x8*>(&Abuf[APL + base]) = lv;
      }
    } else if constexpr (IMODE == IN_MERGE) {
      const f16* vrep = reinterpret_cast<const f16*>(in);
      const int bb = iz / 3, jjm = iz % 3;
      const int pr0 = jjm * 2;
      for (int i = tid; i < 4 * 66 * 8; i += 512) {
        int ci4 = i & 7;
        int t = i >> 3;
        int xp = t % 66, rr = t / 66;
        int y = y0 + rr - 1, x = xp - 1;
        float4 v = make_float4(0.f, 0.f, 0.f, 0.f);
        if ((unsigned)y < 64u && (unsigned)x < 64u) {
          long bpi = (long)bb * PIXN + y * 64 + x;
          float s0 = s_sm[t * 2], s1 = s_sm[t * 2 + 1];
          const f16* pa = vrep + ((long)pr0 * 16384 + bpi) * 96 + kc * 32 + ci4 * 4;
          const f16* pb = vrep + ((long)(pr0 + 1) * 16384 + bpi) * 96 + kc * 32 + ci4 * 4;
          v.x = s0 * h2f(pa[0]) + s1 * h2f(pb[0]);
          v.y = s0 * h2f(pa[1]) + s1 * h2f(pb[1]);
          v.z = s0 * h2f(pa[2]) + s1 * h2f(pb[2]);
          v.w = s0 * h2f(pa[3]) + s1 * h2f(pb[3]);
        }
        unsigned short h0 = f2bf(v.x), h1 = f2bf(v.y), h2 = f2bf(v.z), h3 = f2bf(v.w);
        u16x4 hv = {h0, h1, h2, h3};
        u16x4 lv = {f2bf(v.x - bf2f(h0)), f2bf(v.y - bf2f(h1)),
                    f2bf(v.z - bf2f(h2)), f2bf(v.w - bf2f(h3))};
        int base = (ci4 >> 1) * AST + (rr * 66 + xp) * 8 + (ci4 & 1) * 4;
        *reinterpret_cast<u16x4*>(&Abuf[base]) = hv;
        *reinterpret_cast<u16x4*>(&Abuf[APL + base]) = lv;
      }
    } else {
      for (int i = tid; i < 4 * 66 * 8; i += 512) {
        int ci4 = i & 7;
        int t = i >> 3;
        int xp = t % 66, rr = t / 66;
        int y = y0 + rr - 1, x = xp - 1;
        float4 v = make_float4(0.f, 0.f, 0.f, 0.f);
        if ((unsigned)y < 64u && (unsigned)x < 64u) {
          long off = (long)(y * 64 + x) * LDV + kc * 32 + ci4 * 4;
          if constexpr (IMODE == IN_UVPAIR) {
            float4 u = *reinterpret_cast<const float4*>(baseA + off);
            float4 w2 = *reinterpret_cast<const float4*>(baseB2 + off);
            float4 bi = *reinterpret_cast<const float4*>(bias_in + kc * 32 + ci4 * 4);
            v.x = u.x + w2.x + bi.x; v.x = v.x >= 0.f ? v.x : 0.1f * v.x;
            v.y = u.y + w2.y + bi.y; v.y = v.y >= 0.f ? v.y : 0.1f * v.y;
            v.z = u.z + w2.z + bi.z; v.z = v.z >= 0.f ? v.z : 0.1f * v.z;
            v.w = u.w + w2.w + bi.w; v.w = v.w >= 0.f ? v.w : 0.1f * v.w;
          } else {
            v = *reinterpret_cast<const float4*>(baseA + off);
          }
        }
        unsigned short h0 = f2bf(v.x), h1 = f2bf(v.y), h2 = f2bf(v.z), h3 = f2bf(v.w);
        u16x4 hv = {h0, h1, h2, h3};
        u16x4 lv = {f2bf(v.x - bf2f(h0)), f2bf(v.y - bf2f(h1)),
                    f2bf(v.z - bf2f(h2)), f2bf(v.w - bf2f(h3))};
        int base = (ci4 >> 1) * AST + (rr * 66 + xp) * 8 + (ci4 & 1) * 4;
        *reinterpret_cast<u16x4*>(&Abuf[base]) = hv;
        *reinterpret_cast<u16x4*>(&Abuf[APL + base]) = lv;
      }
    }
  };

  // ---- init acc ----
  f32x4 acc[MT][NTW];
#pragma unroll
  for (int nt = 0; nt < NTW; ++nt) {
    int co = zoff + (wn * NTW + nt) * 16 + (lane & 15);
    float b0 = 0.f;
    if (bias != nullptr && co < COUT) b0 = bias[co];
#pragma unroll
    for (int mt = 0; mt < MT; ++mt) {
      acc[mt][nt][0] = b0; acc[mt][nt][1] = b0;
      acc[mt][nt][2] = b0; acc[mt][nt][3] = b0;
    }
  }

  // ---- IN_MERGE: per-pixel softmax computed ONCE into LDS ----
  if constexpr (IMODE == IN_MERGE) {
    const float* wbp = in2;
    const int bb = iz / 3, jjm = iz % 3;
    const int pr0 = jjm * 2;
    for (int t = tid; t < 264; t += 512) {
      int rr = t / 66, xp = t - rr * 66;
      int y = y0 + rr - 1, x = xp - 1;
      float s0 = 0.f, s1 = 0.f;
      if ((unsigned)y < 64u && (unsigned)x < 64u) {
        long bpi = (long)bb * PIXN + y * 64 + x;
        float w0 = wbp[(long)pr0 * 16384 + bpi];
        float w1 = wbp[(long)(pr0 + 1) * 16384 + bpi];
        float mx = fmaxf(w0, w1);
        float e0 = expf(w0 - mx), e1 = expf(w1 - mx);
        float inv = 1.f / (e0 + e1);
        s0 = e0 * inv; s1 = e1 * inv;
      }
      s_sm[t * 2] = s0; s_sm[t * 2 + 1] = s1;
    }
    __syncthreads();
  }

  stageA(0);
  __syncthreads();

  // per-lane B fragment offset within a step (elems)
  const int blo = ((lane >> 4) * COUTW + zoff + (wn * NTW) * 16 + (lane & 15)) * 8;

  s16x8 cbh[NTW], cbl[NTW], pbh[NTW], pbl[NTW];
#pragma unroll
  for (int nt = 0; nt < NTW; ++nt) {
    const unsigned short* p = wbe + (long)nt * 128 + blo;
    pbh[nt] = *reinterpret_cast<const s16x8*>(p);
    pbl[nt] = *reinterpret_cast<const s16x8*>(p + TOTB);
  }

  long bo = 0;
#pragma unroll 1
  for (int kc = 0; kc < KC; ++kc) {
#pragma unroll 1
    for (int tap = 0; tap < 9; ++tap) {
      const int dy = tap / 3, dx = tap % 3;
      const bool last = (kc == KC - 1) && (tap == 8);
      const long bo_next = (tap < 8) ? bo + (long)KC * BSTEP : (long)(kc + 1) * BSTEP;

      // rotate prefetched bank into current (v_mov, overlaps MFMA pipe)
#pragma unroll
      for (int nt = 0; nt < NTW; ++nt) { cbh[nt] = pbh[nt]; cbl[nt] = pbl[nt]; }
      // issue ENTIRE next-step B loads now -> full-cluster latency window
      if (!last) {
#pragma unroll
        for (int nt = 0; nt < NTW; ++nt) {
          const unsigned short* np = wbe + bo_next + (long)nt * 128 + blo;
          pbh[nt] = *reinterpret_cast<const s16x8*>(np);
          pbl[nt] = *reinterpret_cast<const s16x8*>(np + TOTB);
        }
      }

      // A fragments for this tap
      s16x8 ah[MT], al[MT];
      {
        int ci8 = lane >> 4;
        int m = lane & 15;
#pragma unroll
        for (int mt = 0; mt < MT; ++mt) {
          int px = (wm * MT + mt) * 16 + m;
          int r = px >> 6, x = px & 63;
          int aoff = ci8 * AST + ((r + dy) * 66 + (x + dx)) * 8;
          ah[mt] = *reinterpret_cast<const s16x8*>(&Abuf[aoff]);
          al[mt] = *reinterpret_cast<const s16x8*>(&Abuf[APL + aoff]);
        }
      }

#pragma unroll
      for (int nt = 0; nt < NTW; ++nt) {
#pragma unroll
        for (int mt = 0; mt < MT; ++mt) {
          acc[mt][nt] = __builtin_amdgcn_mfma_f32_16x16x32_bf16(ah[mt], cbh[nt], acc[mt][nt], 0, 0, 0);
          acc[mt][nt] = __builtin_amdgcn_mfma_f32_16x16x32_bf16(al[mt], cbh[nt], acc[mt][nt], 0, 0, 0);
          acc[mt][nt] = __builtin_amdgcn_mfma_f32_16x16x32_bf16(ah[mt], cbl[nt], acc[mt][nt], 0, 0, 0);
        }
      }
      bo = bo_next;
    }
    if (kc + 1 < KC) {
      __syncthreads();
      stageA(kc + 1);
      __syncthreads();
    }
  }

  // ---- epilogue ----
#pragma unroll
  for (int mt = 0; mt < MT; ++mt) {
#pragma unroll
    for (int nt = 0; nt < NTW; ++nt) {
      int co = zoff + (wn * NTW + nt) * 16 + (lane & 15);
      if (COUTW > COUT && co >= COUT) continue;
#pragma unroll
      for (int r = 0; r < 4; ++r) {
        int px = (wm * MT + mt) * 16 + (lane >> 4) * 4 + r;
        float v = acc[mt][nt][r];
        if constexpr (ACT == ACT_LRELU) v = v >= 0.f ? v : 0.1f * v;
        if constexpr (ACT == ACT_SIG144) {
          if (co >= 144) v = 1.f / (1.f + expf(-v));
        }
        if constexpr (OMODE == OUT_FLAT) {
          const long obase = (long)iz * PIXN + blockIdx.x * 128;
          out[(obase + px) * COUT + co] = v;
        } else if constexpr (OMODE == OUT_BF) {
          unsigned short* outh = reinterpret_cast<unsigned short*>(out);
          long prow = (long)iz * PIXN + blockIdx.x * 128 + px;
          long rec = prow * (COUT * 2) + (co >> 5) * 64 + (co & 31);
          unsigned short h = f2bf(v);
          outh[rec] = h;
          outh[rec + 32] = f2bf(v - bf2f(h));
        } else {
          long oo = (long)iz * ((long)COUT * PIXN) + (long)co * PIXN + blockIdx.x * 128 + px;
          out[oo] = v + resid[oo];
        }
      }
    }
  }
}

// ---------------- attn v3: 2 px/wave, 3 ch/lane, LDS-precomputed bilinear setup ----------------
// blockIdx.x XCD-swizzled: each XCD gets a contiguous 256-block chunk (2048 px)
// -> kimg gather rows (~2.7 MB) fit the per-XCD 4 MB L2.
#define CWSLOT 580  // 72*8 + 4 pad
__global__ __launch_bounds__(256) void attn3_k(const float* __restrict__ qkv,
                                               const float* __restrict__ om,
                                               float* __restrict__ w_buf,
                                               f16* __restrict__ vre) {
  const int pair = blockIdx.y;
  const int jj = pair >> 1, rr = pair & 1;
  const int ii = (rr == 0) ? (jj == 0 ? 1 : 0) : (jj == 2 ? 1 : 2);
  const int wv = threadIdx.x >> 6;
  const int lane = threadIdx.x & 63;
  const int xs = (blockIdx.x & 7) * 256 + (blockIdx.x >> 3);  // bijective, 2048%8==0
  const int bp0 = xs * 8 + wv * 2;  // even; both px same b

  __shared__ float s_om[8 * 216];
  __shared__ float s_cw[8 * CWSLOT];

  {
    const float* omrow = om + ((long)pair * 16384 + bp0) * 216;
    float* dst = s_om + wv * 432;
    for (int i = lane; i < 432; i += 64) dst[i] = omrow[i];
  }
  __syncthreads();

  for (int t = lane; t < 144; t += 64) {
    int ph = t / 72, cmb = t - ph * 72;
    int g = cmb / 9, n = cmb - g * 9;
    int p = (bp0 + ph) & 4095;
    int y = p >> 6, x = p & 63;
    const float* so = s_om + (wv * 2 + ph) * 216;
    float oy = so[g * 9 + n], ox = so[72 + g * 9 + n], m = so[144 + g * 9 + n];
    float py = oy + (float)(y + n / 3 - 1);
    float px = ox + (float)(x + n % 3 - 1);
    float y0f = floorf(py), x0f = floorf(px);
    float wy = py - y0f, wx = px - x0f;
    float* dst = s_cw + (wv * 2 + ph) * CWSLOT + cmb * 8;
#pragma unroll
    for (int dy = 0; dy < 2; ++dy) {
#pragma unroll
      for (int dx = 0; dx < 2; ++dx) {
        float yc = y0f + dy, xc = x0f + dx;
        bool valid = (yc >= 0.f) & (yc < 64.f) & (xc >= 0.f) & (xc < 64.f);
        float w = (dy ? wy : 1.f - wy) * (dx ? wx : 1.f - wx) * m;
        w = valid ? w : 0.f;
        int yi = (int)fminf(fmaxf(yc, 0.f), 63.f);
        int xi = (int)fminf(fmaxf(xc, 0.f), 63.f);
        int idx = (yi * 64 + xi) * 288 + 96;  // K base; V adds +96
        dst[dy * 2 + dx] = w;
        dst[4 + dy * 2 + dx] = __int_as_float(idx);
      }
    }
  }
  __syncthreads();

  const int ph = lane >> 5;
  const int li = lane & 31;
  const int bp = bp0 + ph;
  const int b = bp >> 12;
  const int cb = li * 3;
  const int g = li >> 2;
  const float* kimg = qkv + (long)(b * 3 + ii) * (PIXN * 288);
  const float* qrow = qkv + ((long)(b * 3 + jj) * PIXN + (bp & 4095)) * 288 + cb;
  const float q0 = qrow[0], q1 = qrow[1], q2 = qrow[2];
  const float* cw = s_cw + (wv * 2 + ph) * CWSLOT + g * 9 * 8;

  float ka[9][3];
  float rel[9];
#pragma unroll
  for (int n = 0; n < 9; ++n) {
    float4 w4 = *reinterpret_cast<const float4*>(cw + n * 8);
    float4 i4 = *reinterpret_cast<const float4*>(cw + n * 8 + 4);
    int ia = __float_as_int(i4.x) + cb, ib = __float_as_int(i4.y) + cb;
    int ic = __float_as_int(i4.z) + cb, id = __float_as_int(i4.w) + cb;
#pragma unroll
    for (int j = 0; j < 3; ++j) {
      float a = w4.x * kimg[ia + j];
      a = fmaf(w4.y, kimg[ib + j], a);
      a = fmaf(w4.z, kimg[ic + j], a);
      a = fmaf(w4.w, kimg[id + j], a);
      ka[n][j] = a;
    }
    float part = q0 * ka[n][0];
    part = fmaf(q1, ka[n][1], part);
    part = fmaf(q2, ka[n][2], part);
#pragma unroll
    for (int off = 16; off > 0; off >>= 1) part += __shfl_xor(part, off, 64);
    rel[n] = part;
  }

  int i0 = 0; float v0 = rel[0];
  float ks0a = ka[0][0], ks0b = ka[0][1], ks0c = ka[0][2];
#pragma unroll
  for (int n = 1; n < 9; ++n) {
    bool t = rel[n] > v0;
    v0 = t ? rel[n] : v0; i0 = t ? n : i0;
    ks0a = t ? ka[n][0] : ks0a; ks0b = t ? ka[n][1] : ks0b; ks0c = t ? ka[n][2] : ks0c;
  }
  int i1 = 0; float v1 = -3.4e38f;
  float ks1a = 0.f, ks1b = 0.f, ks1c = 0.f;
#pragma unroll
  for (int n = 0; n < 9; ++n) {
    bool t = (n != i0) && rel[n] > v1;
    v1 = t ? rel[n] : v1; i1 = t ? n : i1;
    ks1a = t ? ka[n][0] : ks1a; ks1b = t ? ka[n][1] : ks1b; ks1c = t ? ka[n][2] : ks1c;
  }
  float e = expf(v1 - v0);
  float cw0 = 1.f / (1.f + e), cw1 = e * cw0;

  float wpart = q0 * (cw0 * ks0a + cw1 * ks1a);
  wpart = fmaf(q1, cw0 * ks0b + cw1 * ks1b, wpart);
  wpart = fmaf(q2, cw0 * ks0c + cw1 * ks1c, wpart);
#pragma unroll
  for (int off = 16; off > 0; off >>= 1) wpart += __shfl_xor(wpart, off, 64);
  if (li == 0) w_buf[(long)pair * 16384 + bp] = wpart;

  float4 wA = *reinterpret_cast<const float4*>(cw + i0 * 8);
  float4 iA = *reinterpret_cast<const float4*>(cw + i0 * 8 + 4);
  float4 wB = *reinterpret_cast<const float4*>(cw + i1 * 8);
  float4 iB = *reinterpret_cast<const float4*>(cw + i1 * 8 + 4);
  int a0 = __float_as_int(iA.x) + 96 + cb, a1 = __float_as_int(iA.y) + 96 + cb;
  int a2 = __float_as_int(iA.z) + 96 + cb, a3 = __float_as_int(iA.w) + 96 + cb;
  int b0 = __float_as_int(iB.x) + 96 + cb, b1 = __float_as_int(iB.y) + 96 + cb;
  int b2 = __float_as_int(iB.z) + 96 + cb, b3 = __float_as_int(iB.w) + 96 + cb;
  f16* vrow = vre + ((long)pair * 16384 + bp) * 96 + cb;
#pragma unroll
  for (int j = 0; j < 3; ++j) {
    float va = wA.x * kimg[a0 + j];
    va = fmaf(wA.y, kimg[a1 + j], va);
    va = fmaf(wA.z, kimg[a2 + j], va);
    va = fmaf(wA.w, kimg[a3 + j], va);
    float vb = wB.x * kimg[b0 + j];
    vb = fmaf(wB.y, kimg[b1 + j], vb);
    vb = fmaf(wB.z, kimg[b2 + j], vb);
    vb = fmaf(wB.w, kimg[b3 + j], vb);
    vrow[j] = f2h(cw0 * va + cw1 * vb);
  }
}

// ---------------- host ----------------
extern "C" void kernel_launch(void* const* d_in, const int* in_sizes, int n_in,
                              void* d_out, int out_size, void* d_ws, size_t ws_size,
                              hipStream_t stream) {
  const float* fea = (const float*)d_in[0];
  const float* cf_w = (const float*)d_in[1];
  const float* cf_b = (const float*)d_in[2];
  const float* wq = (const float*)d_in[3];
  const float* bq = (const float*)d_in[4];
  const float* wk = (const float*)d_in[5];
  const float* bk = (const float*)d_in[6];
  const float* wv = (const float*)d_in[7];
  const float* bv = (const float*)d_in[8];
  const float* oc1_w = (const float*)d_in[9];
  const float* oc1_b = (const float*)d_in[10];
  const float* oc2_w = (const float*)d_in[11];
  const float* oc2_b = (const float*)d_in[12];
  const float* om_w = (const float*)d_in[13];
  const float* om_b = (const float*)d_in[14];
  const float* cl_w = (const float*)d_in[15];
  const float* cl_b = (const float*)d_in[16];

  char* base = (char*)d_ws;
  size_t o = 0;
  auto carve = [&](size_t bytes) { char* p = base + o; o += (bytes + 255) & ~255UL; return p; };

  unsigned short* WBQ = (unsigned short*)carve(2UL * 165888 * 2);  // composite qkv conv
  float* BQ = (float*)carve(288UL * 4);
  unsigned short* WB1 = (unsigned short*)carve(2UL * 2 * 82944 * 2);  // [sel][hi|lo]
  unsigned short* WB2 = (unsigned short*)carve(2UL * 82944 * 2);
  unsigned short* WB3 = (unsigned short*)carve(2UL * 221184 * 2);     // om, COUTP=256
  unsigned short* WB4 = (unsigned short*)carve(2UL * 55296 * 2);
  unsigned short* feaB = (unsigned short*)carve(12UL * PIXN * 128 * 2);  // interleaved bf16

  float* om_t = (float*)carve(21233664UL * 4);
  float* qkv_t = (float*)carve(14155776UL * 4);
  float* U_t = (float*)carve(4718592UL * 4);
  float* V_t = (float*)carve(4718592UL * 4);
  unsigned short* off2B = (unsigned short*)carve(24UL * PIXN * 192 * 2);  // interleaved bf16
  float* w_buf = (float*)carve(98304UL * 4);
  f16* vre_b = (f16*)V_t;

  // --- weight prep + fea transpose (7 jobs on grid.y) ---
  prep_all<<<dim3(864, 7), 256, 0, stream>>>(cf_w, oc1_w, oc2_w, om_w, cl_w,
                                             wq, wk, wv, bq, bk, bv, cf_b, fea,
                                             WBQ, BQ, WB1, WB2, WB3, WB4, feaB);

  // --- fused emb+qkv conv (MFMA bf16x3, composite weights), co split in 3 ---
  conv3x3r<64, 288, 288, 3, IN_BF, ACT_NONE, OUT_FLAT, 2><<<dim3(32, 12, 3), 512, 0, stream>>>(
      (const float*)feaB, nullptr, nullptr, WBQ, BQ, qkv_t, nullptr);

  // --- off1 split (MFMA bf16x3): U = convA(q_img), V = convB(k_img) ---
  conv3x3r<96, 96, 96, 1, IN_QKV, ACT_NONE, OUT_FLAT, 2><<<dim3(32, 24, 1), 512, 0, stream>>>(
      qkv_t, nullptr, nullptr, WB1, nullptr, U_t, nullptr);

  // --- off2 (MFMA bf16x3) with fused off1 epilogue -> interleaved bf16 records ---
  conv3x3r<96, 96, 96, 1, IN_UVPAIR, ACT_LRELU, OUT_BF, 2><<<dim3(32, 24, 1), 512, 0, stream>>>(
      U_t, V_t, oc1_b, WB2, oc2_b, (float*)off2B, nullptr);

  // --- om conv (MFMA bf16x3, WN=4/PF=0 proven config) + fused sigmoid ---
  conv3x3r<96, 216, 256, 2, IN_BF, ACT_SIG144, OUT_FLAT, 4><<<dim3(32, 24, 2), 512, 0, stream>>>(
      (const float*)off2B, nullptr, nullptr, WB3, om_b, om_t, nullptr);

  // --- fused deformable attention (fp32; 2 px/wave, 3 ch/lane, LDS setup, XCD swizzle) ---
  attn3_k<<<dim3(2048, 6), 256, 0, stream>>>(qkv_t, om_t, w_buf, vre_b);

  // --- final conv (MFMA bf16x3) with FUSED merge staging (per-pixel softmax in LDS) ---
  conv3x3r<96, 64, 64, 1, IN_MERGE, ACT_NONE, OUT_NCHWRES, 2><<<dim3(32, 12, 1), 512, 0, stream>>>(
      (const float*)vre_b, w_buf, nullptr, WB4, cl_b, (float*)d_out, fea);
}